// Round 15
// baseline (85.266 us; speedup 1.0000x reference)
//
#include <hip/hip_runtime.h>

// Fused masked 3x3 conv x2 (MinkowskiConv stride-1 equivalent), fp32:
//   m   = float(mask)
//   h   = relu((conv3x3(x*m, w1) + b1) * m)
//   out = (conv3x3(h, w2) + b2) * m
// Round-11 access discipline (LDS tile, aligned b128 staging, enc-sign mask
// folding, stride-1 scalar conv1/conv2 reads, conv2 vertical register
// rolling, NON-TEMPORAL stores) on a TALLER tile: 128x32, 512 threads.
// Halo read amplification drops 1.33x -> 1.19x (the last first-order
// traffic term); LDS 38.1 KB -> 4 blocks x 8 waves = 32 waves/CU.

#define TB_W 128           // output tile width
#define TB_H 32            // output tile height
#define SX   136           // staged width: TB_W + 8 (16B-aligned halo)
#define SY   36            // staged height: TB_H + 4
#define NV4  (SX / 4)      // 34 float4 per staged row
#define NSTG (SY * NV4)    // 1224
#define HX   130           // h region width  (TB_W + 2)
#define HY   34            // h region height (TB_H + 2)
#define NH   (HX * HY)     // 4420 h points
#define NTHR 512

__global__ __launch_bounds__(NTHR) void fused_mconv2(
    const float* __restrict__ x, const int* __restrict__ mask,
    const float* __restrict__ w1p, const float* __restrict__ b1p,
    const float* __restrict__ w2p, const float* __restrict__ b2p,
    float* __restrict__ out, int H, int W)
{
    __shared__ __align__(16) float s_xm[SY][SX];   // x*m over halo-2 region
    __shared__ __align__(16) float s_hm[HY][SX];   // stage: m; after conv1: enc

    const int tid  = threadIdx.y * 64 + threadIdx.x;     // block (64,8)
    const int c0   = blockIdx.x * TB_W;
    const int row0 = blockIdx.y * TB_H;
    const size_t plane = (size_t)H * W;
    const float* xb = x    + (size_t)blockIdx.z * plane;
    const int*   mb = mask + (size_t)blockIdx.z * plane;
    float*       ob = out  + (size_t)blockIdx.z * plane;

    float W1[9], W2[9];
    #pragma unroll
    for (int i = 0; i < 9; ++i) { W1[i] = w1p[i]; W2[i] = w2p[i]; }
    const float B1 = b1p[0], B2 = b2p[0];

    // ---- stage: x*m and m (both aligned float4), origin (row0-2, c0-4) ----
    // s_hm row hr holds mask/enc of h image row row0-1+hr (stage row hr+1).
    for (int idx = tid; idx < NSTG; idx += NTHR) {
        const int row  = idx / NV4;
        const int col4 = idx - row * NV4;
        const int r = row0 - 2 + row;
        const int c = c0 - 4 + (col4 << 2);
        float4 xm = make_float4(0.f, 0.f, 0.f, 0.f);
        float4 mm = make_float4(0.f, 0.f, 0.f, 0.f);
        if (r >= 0 && r < H && c >= 0 && c < W) {   // c%4==0, W%4==0 -> all-or-nothing
            const size_t g = (size_t)r * W + c;
            const float4 xv = *reinterpret_cast<const float4*>(xb + g);
            const int4   mi = *reinterpret_cast<const int4*>(mb + g);
            mm = make_float4((float)mi.x, (float)mi.y, (float)mi.z, (float)mi.w);
            xm = make_float4(xv.x * mm.x, xv.y * mm.y, xv.z * mm.z, xv.w * mm.w);
        }
        *reinterpret_cast<float4*>(&s_xm[row][col4 << 2]) = xm;
        if (row >= 1 && row <= HY)                  // stage rows 1..34 -> s_hm 0..33
            *reinterpret_cast<float4*>(&s_hm[row - 1][col4 << 2]) = mm;
    }
    __syncthreads();

    // ---- conv1: enc = m ? relu(conv(x*m)+b1) : -1, over 130x34 h region ----
    // h point (hr,hcol) = image (row0-1+hr, c0-1+hcol); taps s_xm[hr+di]
    // [hcol+2+dj]; own mask/enc word at s_hm[hr][hcol+3] (same thread RMW).
    for (int idx = tid; idx < NH; idx += NTHR) {
        const int hr   = idx / HX;
        const int hcol = idx - hr * HX;
        const float m = s_hm[hr][hcol + 3];
        float acc = B1;
        #pragma unroll
        for (int di = 0; di < 3; ++di)
            #pragma unroll
            for (int dj = 0; dj < 3; ++dj)
                acc += W1[di * 3 + dj] * s_xm[hr + di][hcol + 2 + dj];
        const float h = acc > 0.f ? acc : 0.f;
        s_hm[hr][hcol + 3] = (m > 0.5f) ? h : -1.0f;
    }
    __syncthreads();

    // ---- conv2: column-per-lane vertical register rolling, NT stores ----
    // d_k(hr) = W2row[k] . relu(s_hm[hr][j+3..j+5]);
    // out(i,j) = d0(i) + d1(i+1) + d2(i+2) + B2, mask = enc sign at
    // s_hm[i+1][j+4]. Strip of 8 rows per thread, 10 iters (2 prime).
    {
        const int j     = tid & 127;        // output column
        const int strip = tid >> 7;         // 0..3
        const int i0    = strip << 3;       // rows i0 .. i0+7
        float P = 0.f, Q = 0.f, cm = 0.f;
        #pragma unroll
        for (int t = 0; t < 10; ++t) {
            const int hr = i0 + t;
            const float* rowp = &s_hm[hr][0];
            const float t0 = rowp[j + 3];
            const float t1 = rowp[j + 4];
            const float t2 = rowp[j + 5];
            const float r0 = t0 > 0.f ? t0 : 0.f;
            const float r1 = t1 > 0.f ? t1 : 0.f;
            const float r2 = t2 > 0.f ? t2 : 0.f;
            const float d0 = W2[0] * r0 + W2[1] * r1 + W2[2] * r2;
            const float d1 = W2[3] * r0 + W2[4] * r1 + W2[5] * r2;
            const float d2 = W2[6] * r0 + W2[7] * r1 + W2[8] * r2;
            if (t >= 2) {
                const int i = i0 + t - 2;
                const float v = (cm >= 0.f) ? (Q + d2 + B2) : 0.f;
                __builtin_nontemporal_store(
                    v, ob + (size_t)(row0 + i) * W + (c0 + j));
            }
            Q  = P + d1;
            P  = d0;
            cm = t1;       // enc center for next emit (hr = i+1)
        }
    }
}

extern "C" void kernel_launch(void* const* d_in, const int* in_sizes, int n_in,
                              void* d_out, int out_size, void* d_ws, size_t ws_size,
                              hipStream_t stream) {
    const float* x    = (const float*)d_in[0];
    const int*   mask = (const int*)  d_in[1];
    const float* w1   = (const float*)d_in[2];
    const float* b1   = (const float*)d_in[3];
    const float* w2   = (const float*)d_in[4];
    const float* b2   = (const float*)d_in[5];
    float*       out  = (float*)d_out;

    const int H = 2048, W = 2048;
    const int B = in_sizes[0] / (H * W);

    dim3 block(64, 8, 1);
    dim3 grid(W / TB_W, H / TB_H, B);   // 16 x 64 x 8
    hipLaunchKernelGGL(fused_mconv2, grid, block, 0, stream,
                       x, mask, w1, b1, w2, b2, out, H, W);
}

// Round 16
// 73.998 us; speedup vs baseline: 1.1523x; 1.1523x over previous
//
#include <hip/hip_runtime.h>

// Fused masked 3x3 conv x2 (MinkowskiConv stride-1 equivalent), fp32:
//   m   = float(mask)
//   h   = relu((conv3x3(x*m, w1) + b1) * m)
//   out = (conv3x3(h, w2) + b2) * m
// Round-11 kernel (best measured: LDS tile, enc-sign mask folding,
// conflict-free scalar conv1, conv2 vertical register rolling, NT stores)
// + XCD-AWARE BLOCK SWIZZLE (T1): the flat block id is remapped so each
// XCD gets one contiguous chunk = ONE batch image, with tile-row varying
// fastest inside the chunk. Vertically adjacent tiles (which share the
// 4-row staging halo = 20% of reads) then run consecutively on the SAME
// XCD -> halo re-reads become private-L2 hits instead of cross-die traffic.
// Grid total 16384 = 8 XCDs x 2048: chunked remap is bijective.

#define TB_W 128           // output tile width
#define TB_H 16            // output tile height
#define SX   136           // staged width:  TB_W + 8 (16B-aligned halo)
#define SY   20            // staged height: TB_H + 4
#define NV4  (SX / 4)      // 34 float4 per staged row
#define NSTG (SY * NV4)    // 680
#define HX   130           // h region width  (TB_W + 2)
#define HY   18            // h region height (TB_H + 2)
#define NH   (HX * HY)     // 2340 h points
#define IMG_W 2048
#define IMG_H 2048

__global__ __launch_bounds__(256) void fused_mconv2(
    const float* __restrict__ x, const int* __restrict__ mask,
    const float* __restrict__ w1p, const float* __restrict__ b1p,
    const float* __restrict__ w2p, const float* __restrict__ b2p,
    float* __restrict__ out)
{
    __shared__ float s_xm[SY][SX];   // x*m over halo-2 region
    __shared__ float s_hm[SY][SX];   // stage: m; after conv1: enc(h,m)

    // ---- XCD-chunked bijective block swizzle ----
    // hw id round-robins across 8 XCDs; give XCD k the contiguous work
    // range [2048k, 2048k+2048): exactly batch image k, tile-row fastest.
    const int hw   = (blockIdx.z * gridDim.y + blockIdx.y) * gridDim.x + blockIdx.x;
    const int xcd  = hw & 7;
    const int slot = hw >> 3;                 // 0..2047
    const int orig = (xcd << 11) + slot;      // bijective chunk remap
    const int ty   = orig & 127;              // tile row    0..127 (fastest)
    const int cl   = orig >> 7;               // column-linear 0..127
    const int tx   = cl & 15;                 // tile col    0..15
    const int tz   = cl >> 4;                 // batch       0..7  (== xcd)

    const int tid  = threadIdx.y * 64 + threadIdx.x;     // block (64,4)
    const int c0   = tx * TB_W;
    const int row0 = ty * TB_H;
    const size_t plane = (size_t)IMG_W * IMG_H;
    const float* xb = x    + (size_t)tz * plane;
    const int*   mb = mask + (size_t)tz * plane;
    float*       ob = out  + (size_t)tz * plane;

    float W1[9], W2[9];
    #pragma unroll
    for (int i = 0; i < 9; ++i) { W1[i] = w1p[i]; W2[i] = w2p[i]; }
    const float B1 = b1p[0], B2 = b2p[0];

    // ---- stage: x*m and m, float4/int4 vector loads, origin (row0-2, c0-4) ----
    for (int idx = tid; idx < NSTG; idx += 256) {
        const int row  = idx / NV4;
        const int col4 = idx - row * NV4;
        const int r = row0 - 2 + row;
        const int c = c0 - 4 + (col4 << 2);
        float4 xm = make_float4(0.f, 0.f, 0.f, 0.f);
        float4 mm = make_float4(0.f, 0.f, 0.f, 0.f);
        if (r >= 0 && r < IMG_H && c >= 0 && c < IMG_W) {   // all-or-nothing 16B
            const size_t g = (size_t)r * IMG_W + c;
            const float4 xv = *reinterpret_cast<const float4*>(xb + g);
            const int4   mi = *reinterpret_cast<const int4*>(mb + g);
            mm = make_float4((float)mi.x, (float)mi.y, (float)mi.z, (float)mi.w);
            xm = make_float4(xv.x * mm.x, xv.y * mm.y, xv.z * mm.z, xv.w * mm.w);
        }
        *reinterpret_cast<float4*>(&s_xm[row][col4 << 2]) = xm;
        *reinterpret_cast<float4*>(&s_hm[row][col4 << 2]) = mm;
    }
    __syncthreads();

    // ---- conv1: enc = m ? relu(conv(x*m)+b1) : -1, over 130x18 h region ----
    for (int idx = tid; idx < NH; idx += 256) {
        const int hrow = idx / HX;
        const int hcol = idx - hrow * HX;
        const float m = s_hm[hrow + 1][hcol + 3];
        float acc = B1;
        #pragma unroll
        for (int di = 0; di < 3; ++di)
            #pragma unroll
            for (int dj = 0; dj < 3; ++dj)
                acc += W1[di * 3 + dj] * s_xm[hrow + di][hcol + 2 + dj];
        const float h = acc > 0.f ? acc : 0.f;
        s_hm[hrow + 1][hcol + 3] = (m > 0.5f) ? h : -1.0f;
    }
    __syncthreads();

    // ---- conv2: column-per-lane register rolling, conflict-free reads ----
    {
        const int j     = tid & 127;        // output column
        const int strip = tid >> 7;         // 0..1
        const int i0    = strip * (TB_H / 2);
        float P = 0.f, Q = 0.f, cm = 0.f;
        #pragma unroll
        for (int t = 1; t <= TB_H / 2 + 2; ++t) {
            const int s = i0 + t;
            const float* rowp = &s_hm[s][0];
            const float t0 = rowp[j + 3];
            const float t1 = rowp[j + 4];
            const float t2 = rowp[j + 5];
            const float r0 = t0 > 0.f ? t0 : 0.f;
            const float r1 = t1 > 0.f ? t1 : 0.f;
            const float r2 = t2 > 0.f ? t2 : 0.f;
            const float d0 = W2[0] * r0 + W2[1] * r1 + W2[2] * r2;
            const float d1 = W2[3] * r0 + W2[4] * r1 + W2[5] * r2;
            const float d2 = W2[6] * r0 + W2[7] * r1 + W2[8] * r2;
            if (t >= 3) {
                const int i = s - 3;
                const float v = (cm >= 0.f) ? (Q + d2 + B2) : 0.f;
                __builtin_nontemporal_store(
                    v, ob + (size_t)(row0 + i) * IMG_W + (c0 + j));
            }
            Q  = P + d1;
            P  = d0;
            cm = t1;
        }
    }
}

extern "C" void kernel_launch(void* const* d_in, const int* in_sizes, int n_in,
                              void* d_out, int out_size, void* d_ws, size_t ws_size,
                              hipStream_t stream) {
    const float* x    = (const float*)d_in[0];
    const int*   mask = (const int*)  d_in[1];
    const float* w1   = (const float*)d_in[2];
    const float* b1   = (const float*)d_in[3];
    const float* w2   = (const float*)d_in[4];
    const float* b2   = (const float*)d_in[5];
    float*       out  = (float*)d_out;

    dim3 block(64, 4, 1);
    dim3 grid(IMG_W / TB_W, IMG_H / TB_H, 8);   // 16 x 128 x 8 = 16384
    hipLaunchKernelGGL(fused_mconv2, grid, block, 0, stream,
                       x, mask, w1, b1, w2, b2, out);
}

// Round 17
// 72.807 us; speedup vs baseline: 1.1711x; 1.0164x over previous
//
#include <hip/hip_runtime.h>

// Fused masked 3x3 conv x2 (MinkowskiConv stride-1 equivalent), fp32:
//   m   = float(mask)
//   h   = relu((conv3x3(x*m, w1) + b1) * m)
//   out = (conv3x3(h, w2) + b2) * m
// Round-13 compute structure (conv1 QUADS: two aligned ds_read_b128 serve 4
// h-points; enc at word hcol, aligned float4 write; conv2 stride-1 taps;
// mask in byte array; NT stores) + Round-16 XCD-AWARE BLOCK SWIZZLE (each
// XCD owns one batch image, tile-row fastest -> vertical-halo L2 hits).
// Rationale: swizzle removed the HBM bottleneck (FETCH 196->144 MB); the
// LDS pipe (conv1's scalar taps) is now co-critical -> cut LDS ops 3x.

#define TB_W 128           // output tile width
#define TB_H 16            // output tile height
#define SX   136           // staged width: TB_W + 8 (16B-aligned halo)
#define SY   20            // staged height: TB_H + 4
#define NV4  (SX / 4)      // 34 float4 chunks per staged row
#define NSTG (SY * NV4)    // 680
#define HR   18            // h rows (image h rows row0-1 .. row0+16)
#define NQR  33            // quads per h row (132 points, 130 used)
#define NQ   (HR * NQR)    // 594
#define IMG_W 2048
#define IMG_H 2048

__global__ __launch_bounds__(256) void fused_mconv2(
    const float* __restrict__ x, const int* __restrict__ mask,
    const float* __restrict__ w1p, const float* __restrict__ b1p,
    const float* __restrict__ w2p, const float* __restrict__ b2p,
    float* __restrict__ out)
{
    __shared__ __align__(16) float s_xm[SY][SX];          // x*m, halo-2 region
    __shared__ __align__(16) float s_hm[HR][SX];          // enc(h,m) at word hcol
    __shared__ __align__(4)  unsigned char s_mb[HR][SX];  // mask bytes

    // ---- XCD-chunked bijective block swizzle (grid 16384 = 8 x 2048) ----
    const int hw   = (blockIdx.z * gridDim.y + blockIdx.y) * gridDim.x + blockIdx.x;
    const int xcd  = hw & 7;
    const int slot = hw >> 3;                 // 0..2047
    const int orig = (xcd << 11) + slot;      // XCD k owns [2048k, 2048k+2048)
    const int ty   = orig & 127;              // tile row 0..127 (fastest)
    const int cl   = orig >> 7;
    const int tx   = cl & 15;                 // tile col 0..15
    const int tz   = cl >> 4;                 // batch 0..7 (== xcd)

    const int tid  = threadIdx.y * 64 + threadIdx.x;      // block (64,4)
    const int c0   = tx * TB_W;
    const int row0 = ty * TB_H;
    const size_t plane = (size_t)IMG_W * IMG_H;
    const float* xb = x    + (size_t)tz * plane;
    const int*   mb = mask + (size_t)tz * plane;
    float*       ob = out  + (size_t)tz * plane;

    float W1[9], W2[9];
    #pragma unroll
    for (int i = 0; i < 9; ++i) { W1[i] = w1p[i]; W2[i] = w2p[i]; }
    const float B1 = b1p[0], B2 = b2p[0];

    // ---- stage: x*m (float4) + mask bytes (u32), origin (row0-2, c0-4) ----
    // word/byte index = image col - (c0-4); h point hcol <-> image col
    // c0-1+hcol, so its mask byte sits at index hcol+3.
    for (int idx = tid; idx < NSTG; idx += 256) {
        const int row  = idx / NV4;
        const int col4 = idx - row * NV4;
        const int r = row0 - 2 + row;
        const int c = c0 - 4 + (col4 << 2);
        float4 xm = make_float4(0.f, 0.f, 0.f, 0.f);
        unsigned mpack = 0u;
        if (r >= 0 && r < IMG_H && c >= 0 && c < IMG_W) {  // all-or-nothing 16B
            const size_t g = (size_t)r * IMG_W + c;
            const float4 xv = *reinterpret_cast<const float4*>(xb + g);
            const int4   mi = *reinterpret_cast<const int4*>(mb + g);
            xm.x = mi.x ? xv.x : 0.f;
            xm.y = mi.y ? xv.y : 0.f;
            xm.z = mi.z ? xv.z : 0.f;
            xm.w = mi.w ? xv.w : 0.f;
            mpack = (mi.x ? 1u : 0u) | (mi.y ? 256u : 0u) |
                    (mi.z ? 65536u : 0u) | (mi.w ? 16777216u : 0u);
        }
        *reinterpret_cast<float4*>(&s_xm[row][col4 << 2]) = xm;
        if (row >= 1 && row <= HR)                 // mask rows = stage rows 1..18
            *reinterpret_cast<unsigned*>(&s_mb[row - 1][col4 << 2]) = mpack;
    }
    __syncthreads();

    // ---- conv1 QUADS: 4 points/thread, all-aligned b128 taps ----
    // h point hcol taps s_xm[hr+di][hcol+2..hcol+4]; quad hc=4q spans words
    // 4q+2..4q+7 = aligned float4 at [4q] and [4q+4].
    for (int idx = tid; idx < NQ; idx += 256) {
        const int hr = idx / NQR;
        const int q  = idx - hr * NQR;
        const int hc = q << 2;
        float a0 = B1, a1 = B1, a2 = B1, a3 = B1;
        #pragma unroll
        for (int di = 0; di < 3; ++di) {
            const float4 A  = *reinterpret_cast<const float4*>(&s_xm[hr + di][hc]);
            const float4 Bv = *reinterpret_cast<const float4*>(&s_xm[hr + di][hc + 4]);
            const float w0 = W1[di * 3], w1 = W1[di * 3 + 1], w2 = W1[di * 3 + 2];
            a0 += w0 * A.z  + w1 * A.w  + w2 * Bv.x;
            a1 += w0 * A.w  + w1 * Bv.x + w2 * Bv.y;
            a2 += w0 * Bv.x + w1 * Bv.y + w2 * Bv.z;
            a3 += w0 * Bv.y + w1 * Bv.z + w2 * Bv.w;
        }
        // mask bytes hc+3..hc+6 via two aligned u32 reads
        const unsigned mA = *reinterpret_cast<const unsigned*>(&s_mb[hr][hc]);
        const unsigned mB = *reinterpret_cast<const unsigned*>(&s_mb[hr][hc + 4]);
        float4 e;
        e.x = ((mA >> 24) & 255u) ? fmaxf(a0, 0.f) : -1.0f;
        e.y = ( mB        & 255u) ? fmaxf(a1, 0.f) : -1.0f;
        e.z = ((mB >>  8) & 255u) ? fmaxf(a2, 0.f) : -1.0f;
        e.w = ((mB >> 16) & 255u) ? fmaxf(a3, 0.f) : -1.0f;
        *reinterpret_cast<float4*>(&s_hm[hr][hc]) = e;   // aligned
    }
    __syncthreads();

    // ---- conv2: column-per-lane vertical register rolling, NT stores ----
    // out(i,j) taps s_hm rows i..i+2, words j..j+2 (stride-1, conflict-free).
    {
        const int j     = tid & 127;        // output column
        const int strip = tid >> 7;         // 0..1
        const int i0    = strip * (TB_H / 2);
        float P = 0.f, Q = 0.f, cm = 0.f;
        #pragma unroll
        for (int t = 0; t < TB_H / 2 + 2; ++t) {
            const int hr = i0 + t;
            const float* rowp = &s_hm[hr][0];
            const float t0 = rowp[j];
            const float t1 = rowp[j + 1];
            const float t2 = rowp[j + 2];
            const float r0 = t0 > 0.f ? t0 : 0.f;
            const float r1 = t1 > 0.f ? t1 : 0.f;
            const float r2 = t2 > 0.f ? t2 : 0.f;
            const float d0 = W2[0] * r0 + W2[1] * r1 + W2[2] * r2;
            const float d1 = W2[3] * r0 + W2[4] * r1 + W2[5] * r2;
            const float d2 = W2[6] * r0 + W2[7] * r1 + W2[8] * r2;
            if (t >= 2) {
                const int i = i0 + t - 2;
                const float v = (cm >= 0.f) ? (Q + d2 + B2) : 0.f;
                __builtin_nontemporal_store(
                    v, ob + (size_t)(row0 + i) * IMG_W + (c0 + j));
            }
            Q  = P + d1;
            P  = d0;
            cm = t1;       // enc center (h row i0+t-1, image col j)
        }
    }
}

extern "C" void kernel_launch(void* const* d_in, const int* in_sizes, int n_in,
                              void* d_out, int out_size, void* d_ws, size_t ws_size,
                              hipStream_t stream) {
    const float* x    = (const float*)d_in[0];
    const int*   mask = (const int*)  d_in[1];
    const float* w1   = (const float*)d_in[2];
    const float* b1   = (const float*)d_in[3];
    const float* w2   = (const float*)d_in[4];
    const float* b2   = (const float*)d_in[5];
    float*       out  = (float*)d_out;

    dim3 block(64, 4, 1);
    dim3 grid(IMG_W / TB_W, IMG_H / TB_H, 8);   // 16 x 128 x 8 = 16384
    hipLaunchKernelGGL(fused_mconv2, grid, block, 0, stream,
                       x, mask, w1, b1, w2, b2, out);
}